// Round 14
// baseline (65.094 us; speedup 1.0000x reference)
//
#include <hip/hip_runtime.h>

// FK object-translation scan, round 14: TA-throughput discriminating probe.
// r13 structure (best, 60.6us: 1024 thr/block, S=4, typed quat-map KS scan)
// with ONE change: rb[36]+hb[24] stay LIVE across the scan; P3's 15 float4
// reloads are deleted (32 -> 17 vector-load instrs/thread, -47% TA/L1
// transactions). Costs VGPR 56->~116 -> 1 block/CU (16 waves, half TLP).
// If the kernel is TA/L1-transaction-bound (stride-144B loads touch ~64
// lines/wave-instr), this wins big; if TLP-bound, it regresses like r7/r11.
// Per-step math identical to rounds 6-13 (passed, absmax 0.5 vs thr 3.18).

#define FSM_ID 0x24  // identity: 0->0,1->1,2->2 (2 bits per state image)

__device__ __forceinline__ int fsm_compose(int f, int g) {  // g first, then f
    int r0 = (f >> (((g     ) & 3) << 1)) & 3;
    int r1 = (f >> (((g >> 2) & 3) << 1)) & 3;
    int r2 = (f >> (((g >> 4) & 3) << 1)) & 3;
    return r0 | (r1 << 2) | (r2 << 4);
}

// ---------- quaternion helpers (q = {w,x,y,z}, R(q1*q2)=R(q1)R(q2)) --------
__device__ __forceinline__ void qmul(const float* a, const float* b, float* o) {
    o[0] = a[0]*b[0] - a[1]*b[1] - a[2]*b[2] - a[3]*b[3];
    o[1] = a[0]*b[1] + a[1]*b[0] + a[2]*b[3] - a[3]*b[2];
    o[2] = a[0]*b[2] - a[1]*b[3] + a[2]*b[0] + a[3]*b[1];
    o[3] = a[0]*b[3] + a[1]*b[2] - a[2]*b[1] + a[3]*b[0];
}

__device__ __forceinline__ void qrot(const float* q, const float* v, float* o) {
    const float ux = q[2]*v[2] - q[3]*v[1];
    const float uy = q[3]*v[0] - q[1]*v[2];
    const float uz = q[1]*v[1] - q[2]*v[0];
    const float tx = ux + q[0]*v[0];
    const float ty = uy + q[0]*v[1];
    const float tz = uz + q[0]*v[2];
    o[0] = fmaf(2.f, q[2]*tz - q[3]*ty, v[0]);
    o[1] = fmaf(2.f, q[3]*tx - q[1]*tz, v[1]);
    o[2] = fmaf(2.f, q[1]*ty - q[2]*tx, v[2]);
}

// row-major rotation matrix -> unit quaternion (robust 4-case + normalize)
__device__ __forceinline__ void mat2quat(const float* m, float* q) {
    const float tr = m[0] + m[4] + m[8];
    float qw, qx, qy, qz;
    if (tr > 0.f) {
        const float S = sqrtf(tr + 1.0f) * 2.f, iS = 1.f / S;
        qw = 0.25f * S;
        qx = (m[7] - m[5]) * iS;
        qy = (m[2] - m[6]) * iS;
        qz = (m[3] - m[1]) * iS;
    } else if (m[0] > m[4] && m[0] > m[8]) {
        const float S = sqrtf(1.0f + m[0] - m[4] - m[8]) * 2.f, iS = 1.f / S;
        qw = (m[7] - m[5]) * iS;
        qx = 0.25f * S;
        qy = (m[1] + m[3]) * iS;
        qz = (m[2] + m[6]) * iS;
    } else if (m[4] > m[8]) {
        const float S = sqrtf(1.0f + m[4] - m[0] - m[8]) * 2.f, iS = 1.f / S;
        qw = (m[2] - m[6]) * iS;
        qx = (m[1] + m[3]) * iS;
        qy = 0.25f * S;
        qz = (m[5] + m[7]) * iS;
    } else {
        const float S = sqrtf(1.0f + m[8] - m[0] - m[4]) * 2.f, iS = 1.f / S;
        qw = (m[3] - m[1]) * iS;
        qx = (m[2] + m[6]) * iS;
        qy = (m[5] + m[7]) * iS;
        qz = 0.25f * S;
    }
    const float n = rsqrtf(qw*qw + qx*qx + qy*qy + qz*qz);
    q[0] = qw*n; q[1] = qx*n; q[2] = qy*n; q[3] = qz*n;
}

// quat map: qp[0..3], cp[4..6], qw[7..10], cw[11..13]; tags rp,rw (0=p,1=w)
__device__ __forceinline__ void qmap_compose(
    const float* L, int Lrp, int Lrw,
    const float* E, int Erp, int Erw,
    float* O, int& Orp, int& Orw)
{
    float eq[4], ec[3], r[3];
    #pragma unroll
    for (int i = 0; i < 4; ++i) eq[i] = Lrp ? E[7+i] : E[i];
    #pragma unroll
    for (int i = 0; i < 3; ++i) ec[i] = Lrp ? E[11+i] : E[4+i];
    qmul(L, eq, O);
    qrot(L, ec, r);
    O[4] = r[0] + L[4]; O[5] = r[1] + L[5]; O[6] = r[2] + L[6];
    Orp = Lrp ? Erw : Erp;
    #pragma unroll
    for (int i = 0; i < 4; ++i) eq[i] = Lrw ? E[7+i] : E[i];
    #pragma unroll
    for (int i = 0; i < 3; ++i) ec[i] = Lrw ? E[11+i] : E[4+i];
    qmul(L+7, eq, O+7);
    qrot(L+7, ec, r);
    O[11] = r[0] + L[11]; O[12] = r[1] + L[12]; O[13] = r[2] + L[13];
    Orw = Lrw ? Erw : Erp;
}

__device__ __forceinline__ void qmap_apply(
    const float* m, int rp_, int rw_,
    const float* pin, const float* win, float* pout, float* wout)
{
    float r[3];
    const float* ip = rp_ ? win : pin;
    qrot(m, ip, r);
    pout[0] = r[0] + m[4]; pout[1] = r[1] + m[5]; pout[2] = r[2] + m[6];
    const float* iw = rw_ ? win : pin;
    qrot(m+7, iw, r);
    wout[0] = r[0] + m[11]; wout[1] = r[1] + m[12]; wout[2] = r[2] + m[13];
}

__global__ __launch_bounds__(1024) void fk_scan_par10(
    const float* __restrict__ prob,   // (B,4096,2)
    const float* __restrict__ hands,  // (B,4096,2,3)
    const float* __restrict__ rotm,   // (B,4096,3,3)
    const float* __restrict__ tinit,  // (B,3)
    float* __restrict__ out)          // (B,4096,3)
{
    const int b    = blockIdx.x;
    const int c    = threadIdx.x;     // chunk id 0..1023, 4 steps each
    const int lane = c & 63;
    const int w    = c >> 6;          // wave 0..15

    __shared__ int   sFSM[16];
    __shared__ float sQ[16][14];
    __shared__ int   sQf[16];

    const float* prB = prob  + (size_t)b * 4096 * 2;
    const float* hdB = hands + (size_t)b * 4096 * 6;
    const float* rmB = rotm  + (size_t)b * 4096 * 9;
    float*       obB = out   + (size_t)b * 4096 * 3;

    const float4* pr4 = (const float4*)prB + c * 2;    // 4 steps * 2 / 4
    const float4* hd4 = (const float4*)hdB + c * 6;    // 4 steps * 6 / 4
    const float4* rm4 = (const float4*)rmB + c * 9;    // 4 steps * 9 / 4
    float4*       ob4 = (float4*)obB       + c * 3;    // 4 steps * 3 / 4

    // ---------------- P1: pack 4 contact bits ----------------
    unsigned lcB = 0, rcB = 0;
    #pragma unroll
    for (int i = 0; i < 2; ++i) {
        float4 v = pr4[i];
        lcB |= (unsigned)(v.x > 0.5f) << (2*i);
        rcB |= (unsigned)(v.y > 0.5f) << (2*i);
        lcB |= (unsigned)(v.z > 0.5f) << (2*i+1);
        rcB |= (unsigned)(v.w > 0.5f) << (2*i+1);
    }
    unsigned pL = 0, pR = 0;
    if (c) {
        float2 pv = *(const float2*)(prB + 8*c - 2);   // step 4c-1
        pL = pv.x > 0.5f ? 1u : 0u;
        pR = pv.y > 0.5f ? 1u : 0u;
    }
    unsigned lsB = lcB & ~((lcB << 1) | pL);
    unsigned rsB = rcB & ~((rcB << 1) | pR);
    if (c == 0) { lcB &= ~1u; rcB &= ~1u; lsB &= ~1u; rsB &= ~1u; } // t=0 forced false

    // ---------------- single input load (kept LIVE through the scan) -------
    float rb[36], hb[24];
    #pragma unroll
    for (int j = 0; j < 9; ++j) {
        float4 v = rm4[j];
        rb[4*j]=v.x; rb[4*j+1]=v.y; rb[4*j+2]=v.z; rb[4*j+3]=v.w;
    }
    #pragma unroll
    for (int j = 0; j < 6; ++j) {
        float4 v = hd4[j];
        hb[4*j]=v.x; hb[4*j+1]=v.y; hb[4*j+2]=v.z; hb[4*j+3]=v.w;
    }

    // ---------------- P1b: FSM compose + hierarchical scan ----------------
    int M = FSM_ID;
    #pragma unroll
    for (int k = 0; k < 4; ++k) {
        const unsigned lc = (lcB >> k) & 1u, rc = (rcB >> k) & 1u;
        const unsigned ls = (lsB >> k) & 1u, rs = (rsB >> k) & 1u;
        const int nwi = (int)(ls | rs);
        const int nwe = ls ? 1 : 2;
        const int e0  = lc ? 1 : (rc ? 2 : 0);
        const int e1  = rc ? 2 : (lc ? 1 : 0);
        const int mt  = nwi ? nwe * 0x15 : ((e0 << 2) | (e1 << 4));
        M = fsm_compose(mt, M);
    }
    #pragma unroll
    for (int d = 1; d < 64; d <<= 1) {
        int v  = __shfl_up(M, d);
        int cc = fsm_compose(M, v);
        M = (lane >= d) ? cc : M;
    }
    if (lane == 63) sFSM[w] = M;
    __syncthreads();
    int Pf = FSM_ID;
    for (int i = 0; i < w; ++i) Pf = fsm_compose(sFSM[i], Pf);
    int Me = __shfl_up(M, 1);
    if (lane == 0) Me = FSM_ID;
    const int s_in = fsm_compose(Me, Pf) & 3;   // applied to initial state 0 (cur=-1)

    // ---------------- P2: typed affine compose over 4 steps (matrix form) --
    float Am[24]; int rp = 0, rw = 1;
    #pragma unroll
    for (int i = 0; i < 24; ++i) Am[i] = 0.f;
    Am[0] = Am[4] = Am[8] = 1.f;
    Am[12] = Am[16] = Am[20] = 1.f;
    int s = s_in;
    #pragma unroll
    for (int k = 0; k < 4; ++k) {
        const unsigned lc=(lcB>>k)&1u, rc=(rcB>>k)&1u;
        const unsigned ls=(lsB>>k)&1u, rs=(rsB>>k)&1u;
        const int nwi  = (int)(ls|rs);
        const int c1 = (s==1), c2 = (s==2);
        const int hasc = (c1&(int)lc)|(c2&(int)rc);
        const int haso = (c1&(int)rc)|(c2&(int)lc);
        const int grab = nwi | ((hasc^1)&haso);
        const int gi   = nwi ? (ls?0:1) : c1;
        const int new_s= grab ? gi+1 : (hasc ? s : 0);
        const float* Rk = rb + 9*k;
        const float* Hk = hb + 6*k;
        if (grab) {
            const float hx = gi?Hk[3]:Hk[0], hy = gi?Hk[4]:Hk[1], hz = gi?Hk[5]:Hk[2];
            float t[9];
            #pragma unroll
            for (int i2=0;i2<3;++i2)
                #pragma unroll
                for (int j2=0;j2<3;++j2)
                    t[3*i2+j2] = Rk[i2]*Am[j2] + Rk[3+i2]*Am[3+j2] + Rk[6+i2]*Am[6+j2];
            const float ex=Am[9]-hx, ey=Am[10]-hy, ez=Am[11]-hz;
            Am[21] = Rk[0]*ex + Rk[3]*ey + Rk[6]*ez;
            Am[22] = Rk[1]*ex + Rk[4]*ey + Rk[7]*ez;
            Am[23] = Rk[2]*ex + Rk[5]*ey + Rk[8]*ez;
            #pragma unroll
            for (int i2=0;i2<9;++i2) Am[12+i2] = t[i2];
            rw = rp;
        } else if (new_s) {
            const int ci = new_s - 1;
            const float hx = ci?Hk[3]:Hk[0], hy = ci?Hk[4]:Hk[1], hz = ci?Hk[5]:Hk[2];
            float t[9];
            #pragma unroll
            for (int i2=0;i2<3;++i2)
                #pragma unroll
                for (int j2=0;j2<3;++j2)
                    t[3*i2+j2] = Rk[3*i2]*Am[12+j2] + Rk[3*i2+1]*Am[15+j2] + Rk[3*i2+2]*Am[18+j2];
            const float e0_ = hx + Rk[0]*Am[21] + Rk[1]*Am[22] + Rk[2]*Am[23];
            const float e1_ = hy + Rk[3]*Am[21] + Rk[4]*Am[22] + Rk[5]*Am[23];
            const float e2_ = hz + Rk[6]*Am[21] + Rk[7]*Am[22] + Rk[8]*Am[23];
            #pragma unroll
            for (int i2=0;i2<9;++i2) Am[i2] = t[i2];
            Am[9]=e0_; Am[10]=e1_; Am[11]=e2_;
            rp = rw;
        }
        s = new_s;
    }

    // ---------------- matrix -> quaternion (once per chunk map) ------------
    float Qm[14];
    mat2quat(Am, Qm);          // Mp -> qp
    Qm[4] = Am[9]; Qm[5] = Am[10]; Qm[6] = Am[11];
    mat2quat(Am + 12, Qm + 7); // Mw -> qw
    Qm[11] = Am[21]; Qm[12] = Am[22]; Qm[13] = Am[23];

    // ---------------- quat KS scan (select-based) --------------------------
    #pragma unroll 1
    for (int d = 1; d < 64; d <<= 1) {
        float Em[14];
        #pragma unroll
        for (int i = 0; i < 14; ++i) Em[i] = __shfl_up(Qm[i], d);
        const int Ef = __shfl_up(rp | (rw<<1), d);
        float Om[14]; int orp, orw;
        qmap_compose(Qm, rp, rw, Em, Ef&1, (Ef>>1)&1, Om, orp, orw);
        const bool act = (lane >= d);
        #pragma unroll
        for (int i = 0; i < 14; ++i) Qm[i] = act ? Om[i] : Qm[i];
        rp = act ? orp : rp;
        rw = act ? orw : rw;
    }
    if (lane == 63) {
        #pragma unroll
        for (int i = 0; i < 14; ++i) sQ[w][i] = Qm[i];
        sQf[w] = rp | (rw<<1);
    }
    __syncthreads();

    // wave entry state: <=15 serial 6-float state applies from LDS
    float vp[3] = { tinit[3*b], tinit[3*b+1], tinit[3*b+2] };
    float vw[3] = { 0.f, 0.f, 0.f };
    for (int i = 0; i < w; ++i) {
        float np[3], nw2[3];
        const int f = sQf[i];
        qmap_apply(&sQ[i][0], f & 1, (f >> 1) & 1, vp, vw, np, nw2);
        vp[0]=np[0]; vp[1]=np[1]; vp[2]=np[2];
        vw[0]=nw2[0]; vw[1]=nw2[1]; vw[2]=nw2[2];
    }

    // own inclusive apply, then shift the 6-float STATE from lane-1
    float ipv[3], iwv[3];
    qmap_apply(Qm, rp, rw, vp, vw, ipv, iwv);
    float px = __shfl_up(ipv[0], 1);
    float py = __shfl_up(ipv[1], 1);
    float pz = __shfl_up(ipv[2], 1);
    float Wx = __shfl_up(iwv[0], 1);
    float Wy = __shfl_up(iwv[1], 1);
    float Wz = __shfl_up(iwv[2], 1);
    if (lane == 0) { px=vp[0]; py=vp[1]; pz=vp[2]; Wx=vw[0]; Wy=vw[1]; Wz=vw[2]; }

    // ---------------- P3: exact replay from live registers + output --------
    s = s_in;
    {
        float o[12];
        #pragma unroll
        for (int k = 0; k < 4; ++k) {
            const unsigned lc=(lcB>>k)&1u, rc=(rcB>>k)&1u;
            const unsigned ls=(lsB>>k)&1u, rs=(rsB>>k)&1u;
            const int nwi  = (int)(ls|rs);
            const int c1 = (s==1), c2 = (s==2);
            const int hasc = (c1&(int)lc)|(c2&(int)rc);
            const int haso = (c1&(int)rc)|(c2&(int)lc);
            const int grab = nwi | ((hasc^1)&haso);
            const int gi   = nwi ? (ls?0:1) : c1;
            const int new_s= grab ? gi+1 : (hasc ? s : 0);
            const float* Rk = rb + 9*k;
            const float* Hk = hb + 6*k;
            if (grab) {
                const float hx = gi?Hk[3]:Hk[0], hy = gi?Hk[4]:Hk[1], hz = gi?Hk[5]:Hk[2];
                const float vx = px-hx, vy = py-hy, vz = pz-hz;
                const float d2 = vx*vx + vy*vy + vz*vz;
                if (d2 > 1e-12f) {
                    Wx = Rk[0]*vx + Rk[3]*vy + Rk[6]*vz;
                    Wy = Rk[1]*vx + Rk[4]*vy + Rk[7]*vz;
                    Wz = Rk[2]*vx + Rk[5]*vy + Rk[8]*vz;
                } else {
                    Wx = 0.1f*Rk[6]; Wy = 0.1f*Rk[7]; Wz = 0.1f*Rk[8];
                }
            }
            if (new_s) {
                const int ci = new_s - 1;
                const float hx = ci?Hk[3]:Hk[0], hy = ci?Hk[4]:Hk[1], hz = ci?Hk[5]:Hk[2];
                px = hx + Rk[0]*Wx + Rk[1]*Wy + Rk[2]*Wz;
                py = hy + Rk[3]*Wx + Rk[4]*Wy + Rk[5]*Wz;
                pz = hz + Rk[6]*Wx + Rk[7]*Wy + Rk[8]*Wz;
            }
            s = new_s;
            o[3*k+0]=px; o[3*k+1]=py; o[3*k+2]=pz;
        }
        ob4[0] = make_float4(o[0], o[1], o[2],  o[3]);
        ob4[1] = make_float4(o[4], o[5], o[6],  o[7]);
        ob4[2] = make_float4(o[8], o[9], o[10], o[11]);
    }
}

// ---------------- fallback (any T): wave-per-batch serial scan -----
#define CT 256
__global__ __launch_bounds__(64) void fk_scan_wave(
    const float* __restrict__ prob, const float* __restrict__ hands,
    const float* __restrict__ rotm, const float* __restrict__ tinit,
    float* __restrict__ out, int B, int T)
{
    __shared__ __align__(16) float sP[CT * 2];
    __shared__ __align__(16) float sH[CT * 8];
    __shared__ __align__(16) float sR[CT * 12];
    const int b = blockIdx.x, lane = threadIdx.x;
    const float* prB = prob  + (size_t)b * T * 2;
    const float* hdB = hands + (size_t)b * T * 6;
    const float* rmB = rotm  + (size_t)b * T * 9;
    float*       obB = out   + (size_t)b * T * 3;
    float px = tinit[3*b+0], py = tinit[3*b+1], pz = tinit[3*b+2];
    float Wx = 0.f, Wy = 0.f, Wz = 0.f;
    int cur = -1, prev_l = 0, prev_r = 0;
    for (int t0 = 0; t0 < T; t0 += CT) {
        const int n = (T - t0 < CT) ? (T - t0) : CT;
        for (int i = lane; i < n * 2; i += 64) sP[i] = prB[(size_t)t0*2 + i];
        for (int i = lane; i < n * 6; i += 64) {
            int s2 = i / 6, cc = i - 6*s2; sH[8*s2+cc] = hdB[(size_t)t0*6 + i];
        }
        for (int i = lane; i < n * 9; i += 64) {
            int s2 = i / 9, cc = i - 9*s2; sR[12*s2+cc] = rmB[(size_t)t0*9 + i];
        }
        __syncthreads();
        for (int k = 0; k < n; ++k) {
            const int t = t0 + k;
            const int rl = __builtin_amdgcn_readfirstlane(sP[2*k]   > 0.5f ? 1 : 0);
            const int rr = __builtin_amdgcn_readfirstlane(sP[2*k+1] > 0.5f ? 1 : 0);
            const int nz = (t != 0) ? 1 : 0;
            const int l_c = rl & nz, r_c = rr & nz;
            const int l_s = rl & (prev_l ^ 1) & nz, r_s = rr & (prev_r ^ 1) & nz;
            prev_l = rl; prev_r = rr;
            const int nw = l_s ? 0 : (r_s ? 1 : -1);
            const int hasc = ((cur==0)&l_c) | ((cur==1)&r_c);
            const int haso = ((cur==0)&r_c) | ((cur==1)&l_c);
            const int grab = (nw != -1) | ((hasc^1)&haso);
            const int new_cur = grab ? ((nw!=-1)?nw:(1-cur))
                                     : (((hasc^1)&(cur!=-1)) ? -1 : cur);
            if (new_cur != -1) {
                const float h0x=sH[8*k+0],h0y=sH[8*k+1],h0z=sH[8*k+2];
                const float h1x=sH[8*k+3],h1y=sH[8*k+4],h1z=sH[8*k+5];
                const float R0=sR[12*k+0],R1=sR[12*k+1],R2=sR[12*k+2];
                const float R3=sR[12*k+3],R4=sR[12*k+4],R5=sR[12*k+5];
                const float R6=sR[12*k+6],R7=sR[12*k+7],R8=sR[12*k+8];
                const float hx = new_cur ? h1x : h0x;
                const float hy = new_cur ? h1y : h0y;
                const float hz = new_cur ? h1z : h0z;
                if (grab) {
                    const float vx=px-hx, vy=py-hy, vz=pz-hz;
                    const float d2 = vx*vx+vy*vy+vz*vz;
                    if (d2 > 1e-12f) {
                        Wx = R0*vx+R3*vy+R6*vz; Wy = R1*vx+R4*vy+R7*vz; Wz = R2*vx+R5*vy+R8*vz;
                    } else { Wx = 0.1f*R6; Wy = 0.1f*R7; Wz = 0.1f*R8; }
                }
                px = hx + (R0*Wx+R1*Wy+R2*Wz);
                py = hy + (R3*Wx+R4*Wy+R5*Wz);
                pz = hz + (R6*Wx+R7*Wy+R8*Wz);
            }
            cur = new_cur;
            if (lane == 0) {
                obB[3*(size_t)t+0]=px; obB[3*(size_t)t+1]=py; obB[3*(size_t)t+2]=pz;
            }
        }
        __syncthreads();
    }
}

extern "C" void kernel_launch(void* const* d_in, const int* in_sizes, int n_in,
                              void* d_out, int out_size, void* d_ws, size_t ws_size,
                              hipStream_t stream) {
    const float* prob  = (const float*)d_in[0];
    const float* hands = (const float*)d_in[1];
    const float* rotm  = (const float*)d_in[2];
    const float* tinit = (const float*)d_in[3];
    float* out = (float*)d_out;

    const int B = in_sizes[3] / 3;
    const int T = in_sizes[0] / (B * 2);

    if (T == 4096) {
        hipLaunchKernelGGL(fk_scan_par10, dim3(B), dim3(1024), 0, stream,
                           prob, hands, rotm, tinit, out);
    } else {
        hipLaunchKernelGGL(fk_scan_wave, dim3(B), dim3(64), 0, stream,
                           prob, hands, rotm, tinit, out, B, T);
    }
}

// Round 15
// 60.271 us; speedup vs baseline: 1.0800x; 1.0800x over previous
//
#include <hip/hip_runtime.h>

// FK object-translation scan, FINAL (= round 13, best measured: 60.6us).
// 1024 threads/block, 4 steps/thread, T-parallel via function composition:
//  P1 : pack contact bits; P1b: 3-state FSM map Kogge-Stone scan (exact).
//  P2 : per-thread typed affine map over (p, W=dir*dist), matrix form.
//  mat2quat: SO(3) blocks -> quaternions; KS scan on 14-float quat maps
//  (15 shuffles/round vs 25 matrix, -40% DS traffic).
//  Epilogue: <=15 wave-total state applies + own inclusive apply + 6-float
//  state shuffle from lane-1.  P3: exact replay + float4 stores.
// Counters at 60.6us: VGPR 56 (8 waves/SIMD cap), FETCH 131MB (single clean
// pass), WRITE 24.6MB (zero spill), VALUBusy 37%. Six structural variants
// (r10/r11/r12/r14 etc.) all regressed -4..-11% -> this is the plateau.

#define FSM_ID 0x24  // identity: 0->0,1->1,2->2 (2 bits per state image)

__device__ __forceinline__ int fsm_compose(int f, int g) {  // g first, then f
    int r0 = (f >> (((g     ) & 3) << 1)) & 3;
    int r1 = (f >> (((g >> 2) & 3) << 1)) & 3;
    int r2 = (f >> (((g >> 4) & 3) << 1)) & 3;
    return r0 | (r1 << 2) | (r2 << 4);
}

// ---------- quaternion helpers (q = {w,x,y,z}, R(q1*q2)=R(q1)R(q2)) --------
__device__ __forceinline__ void qmul(const float* a, const float* b, float* o) {
    o[0] = a[0]*b[0] - a[1]*b[1] - a[2]*b[2] - a[3]*b[3];
    o[1] = a[0]*b[1] + a[1]*b[0] + a[2]*b[3] - a[3]*b[2];
    o[2] = a[0]*b[2] - a[1]*b[3] + a[2]*b[0] + a[3]*b[1];
    o[3] = a[0]*b[3] + a[1]*b[2] - a[2]*b[1] + a[3]*b[0];
}

__device__ __forceinline__ void qrot(const float* q, const float* v, float* o) {
    // v' = v + 2 qv x (qv x v + w v)   (unit q)
    const float ux = q[2]*v[2] - q[3]*v[1];
    const float uy = q[3]*v[0] - q[1]*v[2];
    const float uz = q[1]*v[1] - q[2]*v[0];
    const float tx = ux + q[0]*v[0];
    const float ty = uy + q[0]*v[1];
    const float tz = uz + q[0]*v[2];
    o[0] = fmaf(2.f, q[2]*tz - q[3]*ty, v[0]);
    o[1] = fmaf(2.f, q[3]*tx - q[1]*tz, v[1]);
    o[2] = fmaf(2.f, q[1]*ty - q[2]*tx, v[2]);
}

// row-major rotation matrix -> unit quaternion (robust 4-case + normalize)
__device__ __forceinline__ void mat2quat(const float* m, float* q) {
    const float tr = m[0] + m[4] + m[8];
    float qw, qx, qy, qz;
    if (tr > 0.f) {
        const float S = sqrtf(tr + 1.0f) * 2.f, iS = 1.f / S;
        qw = 0.25f * S;
        qx = (m[7] - m[5]) * iS;
        qy = (m[2] - m[6]) * iS;
        qz = (m[3] - m[1]) * iS;
    } else if (m[0] > m[4] && m[0] > m[8]) {
        const float S = sqrtf(1.0f + m[0] - m[4] - m[8]) * 2.f, iS = 1.f / S;
        qw = (m[7] - m[5]) * iS;
        qx = 0.25f * S;
        qy = (m[1] + m[3]) * iS;
        qz = (m[2] + m[6]) * iS;
    } else if (m[4] > m[8]) {
        const float S = sqrtf(1.0f + m[4] - m[0] - m[8]) * 2.f, iS = 1.f / S;
        qw = (m[2] - m[6]) * iS;
        qx = (m[1] + m[3]) * iS;
        qy = 0.25f * S;
        qz = (m[5] + m[7]) * iS;
    } else {
        const float S = sqrtf(1.0f + m[8] - m[0] - m[4]) * 2.f, iS = 1.f / S;
        qw = (m[3] - m[1]) * iS;
        qx = (m[2] + m[6]) * iS;
        qy = (m[5] + m[7]) * iS;
        qz = 0.25f * S;
    }
    const float n = rsqrtf(qw*qw + qx*qx + qy*qy + qz*qz);
    q[0] = qw*n; q[1] = qx*n; q[2] = qy*n; q[3] = qz*n;
}

// quat map: qp[0..3], cp[4..6], qw[7..10], cw[11..13]; tags rp,rw (0=p,1=w)
__device__ __forceinline__ void qmap_compose(
    const float* L, int Lrp, int Lrw,
    const float* E, int Erp, int Erw,
    float* O, int& Orp, int& Orw)
{
    float eq[4], ec[3], r[3];
    // p-output
    #pragma unroll
    for (int i = 0; i < 4; ++i) eq[i] = Lrp ? E[7+i] : E[i];
    #pragma unroll
    for (int i = 0; i < 3; ++i) ec[i] = Lrp ? E[11+i] : E[4+i];
    qmul(L, eq, O);
    qrot(L, ec, r);
    O[4] = r[0] + L[4]; O[5] = r[1] + L[5]; O[6] = r[2] + L[6];
    Orp = Lrp ? Erw : Erp;
    // w-output
    #pragma unroll
    for (int i = 0; i < 4; ++i) eq[i] = Lrw ? E[7+i] : E[i];
    #pragma unroll
    for (int i = 0; i < 3; ++i) ec[i] = Lrw ? E[11+i] : E[4+i];
    qmul(L+7, eq, O+7);
    qrot(L+7, ec, r);
    O[11] = r[0] + L[11]; O[12] = r[1] + L[12]; O[13] = r[2] + L[13];
    Orw = Lrw ? Erw : Erp;
}

__device__ __forceinline__ void qmap_apply(
    const float* m, int rp_, int rw_,
    const float* pin, const float* win, float* pout, float* wout)
{
    float r[3];
    const float* ip = rp_ ? win : pin;
    qrot(m, ip, r);
    pout[0] = r[0] + m[4]; pout[1] = r[1] + m[5]; pout[2] = r[2] + m[6];
    const float* iw = rw_ ? win : pin;
    qrot(m+7, iw, r);
    wout[0] = r[0] + m[11]; wout[1] = r[1] + m[12]; wout[2] = r[2] + m[13];
}

__global__ __launch_bounds__(1024) void fk_scan_par9(
    const float* __restrict__ prob,   // (B,4096,2)
    const float* __restrict__ hands,  // (B,4096,2,3)
    const float* __restrict__ rotm,   // (B,4096,3,3)
    const float* __restrict__ tinit,  // (B,3)
    float* __restrict__ out)          // (B,4096,3)
{
    const int b    = blockIdx.x;
    const int c    = threadIdx.x;     // chunk id 0..1023, 4 steps each
    const int lane = c & 63;
    const int w    = c >> 6;          // wave 0..15

    __shared__ int   sFSM[16];
    __shared__ float sQ[16][14];
    __shared__ int   sQf[16];

    const float* prB = prob  + (size_t)b * 4096 * 2;
    const float* hdB = hands + (size_t)b * 4096 * 6;
    const float* rmB = rotm  + (size_t)b * 4096 * 9;
    float*       obB = out   + (size_t)b * 4096 * 3;

    const float4* pr4 = (const float4*)prB + c * 2;    // 4 steps * 2 / 4
    const float4* hd4 = (const float4*)hdB + c * 6;    // 4 steps * 6 / 4
    const float4* rm4 = (const float4*)rmB + c * 9;    // 4 steps * 9 / 4
    float4*       ob4 = (float4*)obB       + c * 3;    // 4 steps * 3 / 4

    // ---------------- P1: pack 4 contact bits ----------------
    unsigned lcB = 0, rcB = 0;
    #pragma unroll
    for (int i = 0; i < 2; ++i) {
        float4 v = pr4[i];
        lcB |= (unsigned)(v.x > 0.5f) << (2*i);
        rcB |= (unsigned)(v.y > 0.5f) << (2*i);
        lcB |= (unsigned)(v.z > 0.5f) << (2*i+1);
        rcB |= (unsigned)(v.w > 0.5f) << (2*i+1);
    }
    unsigned pL = 0, pR = 0;
    if (c) {
        float2 pv = *(const float2*)(prB + 8*c - 2);   // step 4c-1
        pL = pv.x > 0.5f ? 1u : 0u;
        pR = pv.y > 0.5f ? 1u : 0u;
    }
    unsigned lsB = lcB & ~((lcB << 1) | pL);
    unsigned rsB = rcB & ~((rcB << 1) | pR);
    if (c == 0) { lcB &= ~1u; rcB &= ~1u; lsB &= ~1u; rsB &= ~1u; } // t=0 forced false

    // ---------------- P1b: FSM compose + hierarchical scan ----------------
    int M = FSM_ID;
    #pragma unroll
    for (int k = 0; k < 4; ++k) {
        const unsigned lc = (lcB >> k) & 1u, rc = (rcB >> k) & 1u;
        const unsigned ls = (lsB >> k) & 1u, rs = (rsB >> k) & 1u;
        const int nwi = (int)(ls | rs);
        const int nwe = ls ? 1 : 2;
        const int e0  = lc ? 1 : (rc ? 2 : 0);
        const int e1  = rc ? 2 : (lc ? 1 : 0);
        const int mt  = nwi ? nwe * 0x15 : ((e0 << 2) | (e1 << 4));
        M = fsm_compose(mt, M);
    }
    #pragma unroll
    for (int d = 1; d < 64; d <<= 1) {
        int v  = __shfl_up(M, d);
        int cc = fsm_compose(M, v);
        M = (lane >= d) ? cc : M;
    }
    if (lane == 63) sFSM[w] = M;
    __syncthreads();
    int Pf = FSM_ID;
    for (int i = 0; i < w; ++i) Pf = fsm_compose(sFSM[i], Pf);
    int Me = __shfl_up(M, 1);
    if (lane == 0) Me = FSM_ID;
    const int s_in = fsm_compose(Me, Pf) & 3;   // applied to initial state 0 (cur=-1)

    // ---------------- P2: typed affine compose over 4 steps (matrix form) --
    float Am[24]; int rp = 0, rw = 1;
    #pragma unroll
    for (int i = 0; i < 24; ++i) Am[i] = 0.f;
    Am[0] = Am[4] = Am[8] = 1.f;
    Am[12] = Am[16] = Am[20] = 1.f;
    int s = s_in;
    {
        float rb[36], hb[24];
        #pragma unroll
        for (int j = 0; j < 9; ++j) {
            float4 v = rm4[j];
            rb[4*j]=v.x; rb[4*j+1]=v.y; rb[4*j+2]=v.z; rb[4*j+3]=v.w;
        }
        #pragma unroll
        for (int j = 0; j < 6; ++j) {
            float4 v = hd4[j];
            hb[4*j]=v.x; hb[4*j+1]=v.y; hb[4*j+2]=v.z; hb[4*j+3]=v.w;
        }
        #pragma unroll
        for (int k = 0; k < 4; ++k) {
            const unsigned lc=(lcB>>k)&1u, rc=(rcB>>k)&1u;
            const unsigned ls=(lsB>>k)&1u, rs=(rsB>>k)&1u;
            const int nwi  = (int)(ls|rs);
            const int c1 = (s==1), c2 = (s==2);
            const int hasc = (c1&(int)lc)|(c2&(int)rc);
            const int haso = (c1&(int)rc)|(c2&(int)lc);
            const int grab = nwi | ((hasc^1)&haso);
            const int gi   = nwi ? (ls?0:1) : c1;
            const int new_s= grab ? gi+1 : (hasc ? s : 0);
            const float* Rk = rb + 9*k;
            const float* Hk = hb + 6*k;
            if (grab) {
                const float hx = gi?Hk[3]:Hk[0], hy = gi?Hk[4]:Hk[1], hz = gi?Hk[5]:Hk[2];
                float t[9];
                #pragma unroll
                for (int i2=0;i2<3;++i2)
                    #pragma unroll
                    for (int j2=0;j2<3;++j2)
                        t[3*i2+j2] = Rk[i2]*Am[j2] + Rk[3+i2]*Am[3+j2] + Rk[6+i2]*Am[6+j2];
                const float ex=Am[9]-hx, ey=Am[10]-hy, ez=Am[11]-hz;
                Am[21] = Rk[0]*ex + Rk[3]*ey + Rk[6]*ez;
                Am[22] = Rk[1]*ex + Rk[4]*ey + Rk[7]*ez;
                Am[23] = Rk[2]*ex + Rk[5]*ey + Rk[8]*ez;
                #pragma unroll
                for (int i2=0;i2<9;++i2) Am[12+i2] = t[i2];
                rw = rp;
            } else if (new_s) {
                const int ci = new_s - 1;
                const float hx = ci?Hk[3]:Hk[0], hy = ci?Hk[4]:Hk[1], hz = ci?Hk[5]:Hk[2];
                float t[9];
                #pragma unroll
                for (int i2=0;i2<3;++i2)
                    #pragma unroll
                    for (int j2=0;j2<3;++j2)
                        t[3*i2+j2] = Rk[3*i2]*Am[12+j2] + Rk[3*i2+1]*Am[15+j2] + Rk[3*i2+2]*Am[18+j2];
                const float e0_ = hx + Rk[0]*Am[21] + Rk[1]*Am[22] + Rk[2]*Am[23];
                const float e1_ = hy + Rk[3]*Am[21] + Rk[4]*Am[22] + Rk[5]*Am[23];
                const float e2_ = hz + Rk[6]*Am[21] + Rk[7]*Am[22] + Rk[8]*Am[23];
                #pragma unroll
                for (int i2=0;i2<9;++i2) Am[i2] = t[i2];
                Am[9]=e0_; Am[10]=e1_; Am[11]=e2_;
                rp = rw;
            }
            s = new_s;
        }
    }

    // ---------------- matrix -> quaternion (once per chunk map) ------------
    float Qm[14];
    mat2quat(Am, Qm);          // Mp -> qp
    Qm[4] = Am[9]; Qm[5] = Am[10]; Qm[6] = Am[11];
    mat2quat(Am + 12, Qm + 7); // Mw -> qw
    Qm[11] = Am[21]; Qm[12] = Am[22]; Qm[13] = Am[23];

    // ---------------- quat KS scan (select-based, r9 codegen) --------------
    #pragma unroll 1
    for (int d = 1; d < 64; d <<= 1) {
        float Em[14];
        #pragma unroll
        for (int i = 0; i < 14; ++i) Em[i] = __shfl_up(Qm[i], d);
        const int Ef = __shfl_up(rp | (rw<<1), d);
        float Om[14]; int orp, orw;
        qmap_compose(Qm, rp, rw, Em, Ef&1, (Ef>>1)&1, Om, orp, orw);
        const bool act = (lane >= d);
        #pragma unroll
        for (int i = 0; i < 14; ++i) Qm[i] = act ? Om[i] : Qm[i];
        rp = act ? orp : rp;
        rw = act ? orw : rw;
    }
    if (lane == 63) {
        #pragma unroll
        for (int i = 0; i < 14; ++i) sQ[w][i] = Qm[i];
        sQf[w] = rp | (rw<<1);
    }
    __syncthreads();

    // wave entry state: <=15 serial 6-float state applies from LDS
    float vp[3] = { tinit[3*b], tinit[3*b+1], tinit[3*b+2] };
    float vw[3] = { 0.f, 0.f, 0.f };
    for (int i = 0; i < w; ++i) {
        float np[3], nw2[3];
        const int f = sQf[i];
        qmap_apply(&sQ[i][0], f & 1, (f >> 1) & 1, vp, vw, np, nw2);
        vp[0]=np[0]; vp[1]=np[1]; vp[2]=np[2];
        vw[0]=nw2[0]; vw[1]=nw2[1]; vw[2]=nw2[2];
    }

    // own inclusive apply, then shift the 6-float STATE from lane-1
    float ipv[3], iwv[3];
    qmap_apply(Qm, rp, rw, vp, vw, ipv, iwv);
    float px = __shfl_up(ipv[0], 1);
    float py = __shfl_up(ipv[1], 1);
    float pz = __shfl_up(ipv[2], 1);
    float Wx = __shfl_up(iwv[0], 1);
    float Wy = __shfl_up(iwv[1], 1);
    float Wz = __shfl_up(iwv[2], 1);
    if (lane == 0) { px=vp[0]; py=vp[1]; pz=vp[2]; Wx=vw[0]; Wy=vw[1]; Wz=vw[2]; }

    // ---------------- P3: exact replay + output ----------------
    s = s_in;
    {
        float rb[36], hb[24];
        #pragma unroll
        for (int j = 0; j < 9; ++j) {
            float4 v = rm4[j];
            rb[4*j]=v.x; rb[4*j+1]=v.y; rb[4*j+2]=v.z; rb[4*j+3]=v.w;
        }
        #pragma unroll
        for (int j = 0; j < 6; ++j) {
            float4 v = hd4[j];
            hb[4*j]=v.x; hb[4*j+1]=v.y; hb[4*j+2]=v.z; hb[4*j+3]=v.w;
        }
        float o[12];
        #pragma unroll
        for (int k = 0; k < 4; ++k) {
            const unsigned lc=(lcB>>k)&1u, rc=(rcB>>k)&1u;
            const unsigned ls=(lsB>>k)&1u, rs=(rsB>>k)&1u;
            const int nwi  = (int)(ls|rs);
            const int c1 = (s==1), c2 = (s==2);
            const int hasc = (c1&(int)lc)|(c2&(int)rc);
            const int haso = (c1&(int)rc)|(c2&(int)lc);
            const int grab = nwi | ((hasc^1)&haso);
            const int gi   = nwi ? (ls?0:1) : c1;
            const int new_s= grab ? gi+1 : (hasc ? s : 0);
            const float* Rk = rb + 9*k;
            const float* Hk = hb + 6*k;
            if (grab) {
                const float hx = gi?Hk[3]:Hk[0], hy = gi?Hk[4]:Hk[1], hz = gi?Hk[5]:Hk[2];
                const float vx = px-hx, vy = py-hy, vz = pz-hz;
                const float d2 = vx*vx + vy*vy + vz*vz;
                if (d2 > 1e-12f) {
                    Wx = Rk[0]*vx + Rk[3]*vy + Rk[6]*vz;
                    Wy = Rk[1]*vx + Rk[4]*vy + Rk[7]*vz;
                    Wz = Rk[2]*vx + Rk[5]*vy + Rk[8]*vz;
                } else {
                    Wx = 0.1f*Rk[6]; Wy = 0.1f*Rk[7]; Wz = 0.1f*Rk[8];
                }
            }
            if (new_s) {
                const int ci = new_s - 1;
                const float hx = ci?Hk[3]:Hk[0], hy = ci?Hk[4]:Hk[1], hz = ci?Hk[5]:Hk[2];
                px = hx + Rk[0]*Wx + Rk[1]*Wy + Rk[2]*Wz;
                py = hy + Rk[3]*Wx + Rk[4]*Wy + Rk[5]*Wz;
                pz = hz + Rk[6]*Wx + Rk[7]*Wy + Rk[8]*Wz;
            }
            s = new_s;
            o[3*k+0]=px; o[3*k+1]=py; o[3*k+2]=pz;
        }
        ob4[0] = make_float4(o[0], o[1], o[2],  o[3]);
        ob4[1] = make_float4(o[4], o[5], o[6],  o[7]);
        ob4[2] = make_float4(o[8], o[9], o[10], o[11]);
    }
}

// ---------------- fallback (any T): wave-per-batch serial scan -----
#define CT 256
__global__ __launch_bounds__(64) void fk_scan_wave(
    const float* __restrict__ prob, const float* __restrict__ hands,
    const float* __restrict__ rotm, const float* __restrict__ tinit,
    float* __restrict__ out, int B, int T)
{
    __shared__ __align__(16) float sP[CT * 2];
    __shared__ __align__(16) float sH[CT * 8];
    __shared__ __align__(16) float sR[CT * 12];
    const int b = blockIdx.x, lane = threadIdx.x;
    const float* prB = prob  + (size_t)b * T * 2;
    const float* hdB = hands + (size_t)b * T * 6;
    const float* rmB = rotm  + (size_t)b * T * 9;
    float*       obB = out   + (size_t)b * T * 3;
    float px = tinit[3*b+0], py = tinit[3*b+1], pz = tinit[3*b+2];
    float Wx = 0.f, Wy = 0.f, Wz = 0.f;
    int cur = -1, prev_l = 0, prev_r = 0;
    for (int t0 = 0; t0 < T; t0 += CT) {
        const int n = (T - t0 < CT) ? (T - t0) : CT;
        for (int i = lane; i < n * 2; i += 64) sP[i] = prB[(size_t)t0*2 + i];
        for (int i = lane; i < n * 6; i += 64) {
            int s2 = i / 6, cc = i - 6*s2; sH[8*s2+cc] = hdB[(size_t)t0*6 + i];
        }
        for (int i = lane; i < n * 9; i += 64) {
            int s2 = i / 9, cc = i - 9*s2; sR[12*s2+cc] = rmB[(size_t)t0*9 + i];
        }
        __syncthreads();
        for (int k = 0; k < n; ++k) {
            const int t = t0 + k;
            const int rl = __builtin_amdgcn_readfirstlane(sP[2*k]   > 0.5f ? 1 : 0);
            const int rr = __builtin_amdgcn_readfirstlane(sP[2*k+1] > 0.5f ? 1 : 0);
            const int nz = (t != 0) ? 1 : 0;
            const int l_c = rl & nz, r_c = rr & nz;
            const int l_s = rl & (prev_l ^ 1) & nz, r_s = rr & (prev_r ^ 1) & nz;
            prev_l = rl; prev_r = rr;
            const int nw = l_s ? 0 : (r_s ? 1 : -1);
            const int hasc = ((cur==0)&l_c) | ((cur==1)&r_c);
            const int haso = ((cur==0)&r_c) | ((cur==1)&l_c);
            const int grab = (nw != -1) | ((hasc^1)&haso);
            const int new_cur = grab ? ((nw!=-1)?nw:(1-cur))
                                     : (((hasc^1)&(cur!=-1)) ? -1 : cur);
            if (new_cur != -1) {
                const float h0x=sH[8*k+0],h0y=sH[8*k+1],h0z=sH[8*k+2];
                const float h1x=sH[8*k+3],h1y=sH[8*k+4],h1z=sH[8*k+5];
                const float R0=sR[12*k+0],R1=sR[12*k+1],R2=sR[12*k+2];
                const float R3=sR[12*k+3],R4=sR[12*k+4],R5=sR[12*k+5];
                const float R6=sR[12*k+6],R7=sR[12*k+7],R8=sR[12*k+8];
                const float hx = new_cur ? h1x : h0x;
                const float hy = new_cur ? h1y : h0y;
                const float hz = new_cur ? h1z : h0z;
                if (grab) {
                    const float vx=px-hx, vy=py-hy, vz=pz-hz;
                    const float d2 = vx*vx+vy*vy+vz*vz;
                    if (d2 > 1e-12f) {
                        Wx = R0*vx+R3*vy+R6*vz; Wy = R1*vx+R4*vy+R7*vz; Wz = R2*vx+R5*vy+R8*vz;
                    } else { Wx = 0.1f*R6; Wy = 0.1f*R7; Wz = 0.1f*R8; }
                }
                px = hx + (R0*Wx+R1*Wy+R2*Wz);
                py = hy + (R3*Wx+R4*Wy+R5*Wz);
                pz = hz + (R6*Wx+R7*Wy+R8*Wz);
            }
            cur = new_cur;
            if (lane == 0) {
                obB[3*(size_t)t+0]=px; obB[3*(size_t)t+1]=py; obB[3*(size_t)t+2]=pz;
            }
        }
        __syncthreads();
    }
}

extern "C" void kernel_launch(void* const* d_in, const int* in_sizes, int n_in,
                              void* d_out, int out_size, void* d_ws, size_t ws_size,
                              hipStream_t stream) {
    const float* prob  = (const float*)d_in[0];
    const float* hands = (const float*)d_in[1];
    const float* rotm  = (const float*)d_in[2];
    const float* tinit = (const float*)d_in[3];
    float* out = (float*)d_out;

    const int B = in_sizes[3] / 3;
    const int T = in_sizes[0] / (B * 2);

    if (T == 4096) {
        hipLaunchKernelGGL(fk_scan_par9, dim3(B), dim3(1024), 0, stream,
                           prob, hands, rotm, tinit, out);
    } else {
        hipLaunchKernelGGL(fk_scan_wave, dim3(B), dim3(64), 0, stream,
                           prob, hands, rotm, tinit, out, B, T);
    }
}